// Round 1
// baseline (742.240 us; speedup 1.0000x reference)
//
#include <hip/hip_runtime.h>
#include <hip/hip_bf16.h>

// ---------------- problem constants ----------------
#define D_MODEL 1024
#define N_HEADS 16
#define D_HEAD  64
#define D_FF    4096
#define SEQ     2048
#define BATCH   4
#define NROWS   (BATCH * SEQ)   // 8192

typedef __attribute__((ext_vector_type(8))) short short8;   // 8 x bf16 (4 VGPR)
typedef __attribute__((ext_vector_type(4))) float f32x4;    // mfma accumulator

static __device__ __forceinline__ ushort f2bf(float x) {
  __hip_bfloat16 h = __float2bfloat16(x);
  return *reinterpret_cast<ushort*>(&h);
}

// ---------------- weight packing: out[n][k] (bf16) = in[k][n] (f32) ----------------
// block (32,8); grid (N/32, K/32, batch)
__global__ __launch_bounds__(256) void transpose_pack_b(
    const float* __restrict__ in, ushort* __restrict__ out,
    int K, int N, size_t in_bs, size_t out_bs) {
  in  += (size_t)blockIdx.z * in_bs;
  out += (size_t)blockIdx.z * out_bs;
  __shared__ float tile[32][33];
  int n0 = blockIdx.x * 32, k0 = blockIdx.y * 32;
  int tx = threadIdx.x, ty = threadIdx.y;
#pragma unroll
  for (int i = 0; i < 32; i += 8)
    tile[ty + i][tx] = in[(size_t)(k0 + ty + i) * N + n0 + tx];
  __syncthreads();
#pragma unroll
  for (int i = 0; i < 32; i += 8)
    out[(size_t)(n0 + ty + i) * K + k0 + tx] = f2bf(tile[tx][ty + i]);
}

// ---------------- LayerNorm (f32 in, bf16 out), one block per row of 1024 ----------------
__global__ __launch_bounds__(256) void ln_kernel(
    const float* __restrict__ x, const float* __restrict__ g,
    const float* __restrict__ b, ushort* __restrict__ out) {
  int row = blockIdx.x, t = threadIdx.x;
  const float4 v = *(const float4*)(x + (size_t)row * D_MODEL + t * 4);
  float s  = v.x + v.y + v.z + v.w;
  float ss = v.x * v.x + v.y * v.y + v.z * v.z + v.w * v.w;
#pragma unroll
  for (int off = 1; off < 64; off <<= 1) {
    s  += __shfl_xor(s, off, 64);
    ss += __shfl_xor(ss, off, 64);
  }
  __shared__ float rs_[4], rss_[4];
  int w = t >> 6;
  if ((t & 63) == 0) { rs_[w] = s; rss_[w] = ss; }
  __syncthreads();
  s  = rs_[0] + rs_[1] + rs_[2] + rs_[3];
  ss = rss_[0] + rss_[1] + rss_[2] + rss_[3];
  float mu  = s * (1.0f / D_MODEL);
  float var = ss * (1.0f / D_MODEL) - mu * mu;
  float rstd = rsqrtf(var + 1e-5f);
  float4 gg = *(const float4*)(g + t * 4);
  float4 bb = *(const float4*)(b + t * 4);
  ushort4 r;
  r.x = f2bf((v.x - mu) * rstd * gg.x + bb.x);
  r.y = f2bf((v.y - mu) * rstd * gg.y + bb.y);
  r.z = f2bf((v.z - mu) * rstd * gg.z + bb.z);
  r.w = f2bf((v.w - mu) * rstd * gg.w + bb.w);
  *(ushort4*)(out + (size_t)row * D_MODEL + t * 4) = r;
}

// ---------------- 128x128 bf16 MFMA GEMM, C = A[M][K] * BT[N][K]^T, fused epilogues ----
// MODE 0: QKV  (out0/1/2 = q/k/v bf16, bias0/1/2 = bq/bk/bv, q scaled by 1/8)
// MODE 1: PROJ (out0 f32 = resid + C + bias0)
// MODE 2: FF1  (out0 bf16 = relu(C + bias0))
// MODE 3: FF2  (out0 f32 = resid + C + bias0)
template <int MODE>
__global__ __launch_bounds__(256) void gemm128(
    const ushort* __restrict__ A, const ushort* __restrict__ BT,
    int M, int N, int K,
    const float* __restrict__ bias0, const float* __restrict__ bias1,
    const float* __restrict__ bias2, const float* __restrict__ resid,
    void* __restrict__ out0, void* __restrict__ out1, void* __restrict__ out2) {
  __shared__ __align__(16) ushort As[128 * 32];
  __shared__ __align__(16) ushort Bs[128 * 32];
  const int bm = blockIdx.y, bn = blockIdx.x;
  const int t = threadIdx.x, lane = t & 63, w = t >> 6;
  const int wr = w >> 1, wc = w & 1;
  const int l16 = lane & 15, l4 = lane >> 4;

  f32x4 acc[4][4] = {};

  for (int k0 = 0; k0 < K; k0 += 32) {
    __syncthreads();
#pragma unroll
    for (int i = 0; i < 2; ++i) {
      int c = i * 256 + t;
      int row = c >> 2, e0 = (c & 3) * 8;
      *(uint4*)&As[row * 32 + e0] =
          *(const uint4*)&A[(size_t)(bm * 128 + row) * K + k0 + e0];
      *(uint4*)&Bs[row * 32 + e0] =
          *(const uint4*)&BT[(size_t)(bn * 128 + row) * K + k0 + e0];
    }
    __syncthreads();
    short8 a[4], b[4];
#pragma unroll
    for (int m = 0; m < 4; ++m)
      a[m] = *(const short8*)&As[(wr * 64 + m * 16 + l16) * 32 + l4 * 8];
#pragma unroll
    for (int n = 0; n < 4; ++n)
      b[n] = *(const short8*)&Bs[(wc * 64 + n * 16 + l16) * 32 + l4 * 8];
#pragma unroll
    for (int m = 0; m < 4; ++m)
#pragma unroll
      for (int n = 0; n < 4; ++n)
        acc[m][n] = __builtin_amdgcn_mfma_f32_16x16x32_bf16(a[m], b[n], acc[m][n], 0, 0, 0);
  }

  // epilogue
  const int row0 = bm * 128 + wr * 64, col0 = bn * 128 + wc * 64;
#pragma unroll
  for (int m = 0; m < 4; ++m) {
#pragma unroll
    for (int n = 0; n < 4; ++n) {
      int col = col0 + n * 16 + l16;
      if (MODE == 0) {
        int which = col >> 10;            // uniform within a 16-col fragment
        int c = col & 1023;
        const float* bp_ = (which == 0) ? bias0 : (which == 1) ? bias1 : bias2;
        ushort* op = (which == 0) ? (ushort*)out0 : (which == 1) ? (ushort*)out1 : (ushort*)out2;
        float scale = (which == 0) ? 0.125f : 1.0f;   // fold 1/sqrt(64) into q
#pragma unroll
        for (int i = 0; i < 4; ++i) {
          int row = row0 + m * 16 + l4 * 4 + i;
          float val = (acc[m][n][i] + bp_[c]) * scale;
          op[(size_t)row * D_MODEL + c] = f2bf(val);
        }
      } else if (MODE == 1 || MODE == 3) {
#pragma unroll
        for (int i = 0; i < 4; ++i) {
          int row = row0 + m * 16 + l4 * 4 + i;
          size_t idx = (size_t)row * D_MODEL + col;
          ((float*)out0)[idx] = acc[m][n][i] + bias0[col] + resid[idx];
        }
      } else {  // MODE 2: FF1 relu
#pragma unroll
        for (int i = 0; i < 4; ++i) {
          int row = row0 + m * 16 + l4 * 4 + i;
          float val = fmaxf(acc[m][n][i] + bias0[col], 0.0f);
          ((ushort*)out0)[(size_t)row * D_FF + col] = f2bf(val);
        }
      }
    }
  }
}

// ---------------- causal flash attention ----------------
// grid (SEQ/64, BATCH*N_HEADS), block 256 = 4 waves; wave w owns q rows [qt*64+w*16, +16)
// Q/K/V/O layout: [B, S, H, 64]  (row = b*S + s, col = h*64 + e)
__global__ __launch_bounds__(256) void attn_kernel(
    const ushort* __restrict__ Q, const ushort* __restrict__ Km,
    const ushort* __restrict__ V, ushort* __restrict__ O) {
  const int qt = blockIdx.x;
  const int bh = blockIdx.y;
  const int bb = bh >> 4, hh = bh & 15;
  const int t = threadIdx.x, lane = t & 63, w = t >> 6;
  const int l16 = lane & 15, l4 = lane >> 4;
  const size_t base = (size_t)bb * SEQ * D_MODEL + (size_t)hh * 64;
  const int qb = qt * 64 + w * 16;

  // Q fragments (q already scaled by 1/8)
  short8 aq[2];
#pragma unroll
  for (int kk = 0; kk < 2; ++kk)
    aq[kk] = *(const short8*)&Q[base + (size_t)(qb + l16) * D_MODEL + kk * 32 + l4 * 8];

  f32x4 oacc[4] = {};
  float m_i[4], l_i[4];
#pragma unroll
  for (int i = 0; i < 4; ++i) { m_i[i] = -1e30f; l_i[i] = 0.0f; }

  __shared__ __align__(16) ushort Vt[64 * 64];        // [d][kv], XOR-swizzled
  __shared__ __align__(16) ushort Pl[4][16 * 64];     // per-wave P, XOR-swizzled

  const int nt = qt + 1;
  for (int kt = 0; kt < nt; ++kt) {
    const int kv0 = kt * 64;
    __syncthreads();
    // stage V tile transposed into LDS: Vt[d][kv], col8 swizzled by d&7
#pragma unroll
    for (int i = 0; i < 2; ++i) {
      int c = i * 256 + t;
      int kv = c >> 3, d8 = (c & 7) * 8;
      uint4 vv = *(const uint4*)&V[base + (size_t)(kv0 + kv) * D_MODEL + d8];
      const ushort* pv = (const ushort*)&vv;
#pragma unroll
      for (int j = 0; j < 8; ++j) {
        int d = d8 + j;
        int col = ((((kv >> 3) ^ (d & 7)) << 3) | (kv & 7));
        Vt[d * 64 + col] = pv[j];
      }
    }
    __syncthreads();

    const bool skip = (kv0 > qb + 15);  // wave-uniform
    if (!skip) {
      // S = Q K^T  (scores for 16 q x 64 kv)
      f32x4 sacc[4] = {};
#pragma unroll
      for (int n = 0; n < 4; ++n)
#pragma unroll
        for (int kk = 0; kk < 2; ++kk) {
          short8 bk = *(const short8*)&Km[base + (size_t)(kv0 + n * 16 + l16) * D_MODEL + kk * 32 + l4 * 8];
          sacc[n] = __builtin_amdgcn_mfma_f32_16x16x32_bf16(aq[kk], bk, sacc[n], 0, 0, 0);
        }
      const bool diag = (kv0 + 63 > qb);
      float pf[4][4];   // [n][i]
#pragma unroll
      for (int i = 0; i < 4; ++i) {
        int qg = qb + l4 * 4 + i;
        float mx = -1e30f;
#pragma unroll
        for (int n = 0; n < 4; ++n) {
          float sv = sacc[n][i];
          if (diag && (kv0 + n * 16 + l16 > qg)) sv = -1e30f;
          pf[n][i] = sv;
          mx = fmaxf(mx, sv);
        }
#pragma unroll
        for (int off = 1; off < 16; off <<= 1) mx = fmaxf(mx, __shfl_xor(mx, off, 64));
        float mnew = fmaxf(m_i[i], mx);
        float alpha = __expf(m_i[i] - mnew);
        m_i[i] = mnew;
        float lsum = 0.0f;
#pragma unroll
        for (int n = 0; n < 4; ++n) {
          float pp = __expf(pf[n][i] - mnew);
          pf[n][i] = pp;
          lsum += pp;
        }
#pragma unroll
        for (int off = 1; off < 16; off <<= 1) lsum += __shfl_xor(lsum, off, 64);
        l_i[i] = l_i[i] * alpha + lsum;
#pragma unroll
        for (int nd = 0; nd < 4; ++nd) oacc[nd][i] = oacc[nd][i] * alpha;
      }
      // write P (bf16) to this wave's LDS slice, swizzled like Vt
      ushort* myP = &Pl[w][0];
#pragma unroll
      for (int n = 0; n < 4; ++n)
#pragma unroll
        for (int i = 0; i < 4; ++i) {
          int qr = l4 * 4 + i, kv = n * 16 + l16;
          int col = ((((kv >> 3) ^ (qr & 7)) << 3) | (kv & 7));
          myP[qr * 64 + col] = f2bf(pf[n][i]);
        }
      asm volatile("s_waitcnt lgkmcnt(0)" ::: "memory");
      // O += P V
#pragma unroll
      for (int kk = 0; kk < 2; ++kk) {
        int c8 = kk * 4 + l4;
        short8 ap = *(const short8*)&myP[l16 * 64 + ((c8 ^ (l16 & 7)) << 3)];
#pragma unroll
        for (int nd = 0; nd < 4; ++nd) {
          int d = nd * 16 + l16;
          short8 bv = *(const short8*)&Vt[d * 64 + ((c8 ^ (d & 7)) << 3)];
          oacc[nd] = __builtin_amdgcn_mfma_f32_16x16x32_bf16(ap, bv, oacc[nd], 0, 0, 0);
        }
      }
    }
  }
  // normalize + store
#pragma unroll
  for (int i = 0; i < 4; ++i) {
    int qg = qb + l4 * 4 + i;
    float inv = 1.0f / l_i[i];
#pragma unroll
    for (int nd = 0; nd < 4; ++nd)
      O[base + (size_t)qg * D_MODEL + nd * 16 + l16] = f2bf(oacc[nd][i] * inv);
  }
}

// ---------------- host launch ----------------
extern "C" void kernel_launch(void* const* d_in, const int* in_sizes, int n_in,
                              void* d_out, int out_size, void* d_ws, size_t ws_size,
                              hipStream_t stream) {
  const float* x    = (const float*)d_in[0];
  const float* ln1g = (const float*)d_in[1];
  const float* ln1b = (const float*)d_in[2];
  const float* wq   = (const float*)d_in[3];
  const float* bq   = (const float*)d_in[4];
  const float* wk   = (const float*)d_in[5];
  const float* bk   = (const float*)d_in[6];
  const float* wv   = (const float*)d_in[7];
  const float* bv   = (const float*)d_in[8];
  const float* wp   = (const float*)d_in[9];
  const float* bp   = (const float*)d_in[10];
  const float* ln2g = (const float*)d_in[11];
  const float* ln2b = (const float*)d_in[12];
  const float* w1   = (const float*)d_in[13];
  const float* b1   = (const float*)d_in[14];
  const float* w2   = (const float*)d_in[15];
  const float* b2   = (const float*)d_in[16];
  float* out = (float*)d_out;

  char* base = (char*)d_ws;
  size_t off = 0;
  auto alloc = [&](size_t bytes) -> void* {
    void* r = base + off;
    off += (bytes + 255) & ~(size_t)255;
    return r;
  };
  ushort* WqkvT = (ushort*)alloc((size_t)3 * D_MODEL * D_MODEL * 2);  // [3D][D]
  ushort* WpT   = (ushort*)alloc((size_t)D_MODEL * D_MODEL * 2);      // [D][D]
  ushort* W1T   = (ushort*)alloc((size_t)D_FF * D_MODEL * 2);         // [FF][D]
  ushort* W2T   = (ushort*)alloc((size_t)D_MODEL * D_FF * 2);         // [D][FF]
  ushort* xn    = (ushort*)alloc((size_t)NROWS * D_MODEL * 2);
  ushort* q     = (ushort*)alloc((size_t)NROWS * D_MODEL * 2);
  ushort* k     = (ushort*)alloc((size_t)NROWS * D_MODEL * 2);
  ushort* v     = (ushort*)alloc((size_t)NROWS * D_MODEL * 2);
  ushort* o     = (ushort*)alloc((size_t)NROWS * D_MODEL * 2);
  float*  x2    = (float*) alloc((size_t)NROWS * D_MODEL * 4);
  ushort* xn2   = (ushort*)alloc((size_t)NROWS * D_MODEL * 2);
  ushort* hbuf  = (ushort*)alloc((size_t)NROWS * D_FF * 2);

  dim3 tb(32, 8);
  // pack weights -> bf16 B^T layouts
  transpose_pack_b<<<dim3(2, 32, 16), tb, 0, stream>>>(wq, WqkvT + (size_t)0 * D_MODEL * D_MODEL,
      D_MODEL, D_HEAD, (size_t)D_MODEL * D_HEAD, (size_t)D_HEAD * D_MODEL);
  transpose_pack_b<<<dim3(2, 32, 16), tb, 0, stream>>>(wk, WqkvT + (size_t)1 * D_MODEL * D_MODEL,
      D_MODEL, D_HEAD, (size_t)D_MODEL * D_HEAD, (size_t)D_HEAD * D_MODEL);
  transpose_pack_b<<<dim3(2, 32, 16), tb, 0, stream>>>(wv, WqkvT + (size_t)2 * D_MODEL * D_MODEL,
      D_MODEL, D_HEAD, (size_t)D_MODEL * D_HEAD, (size_t)D_HEAD * D_MODEL);
  transpose_pack_b<<<dim3(32, 32, 1), tb, 0, stream>>>(wp, WpT, D_MODEL, D_MODEL, 0, 0);
  transpose_pack_b<<<dim3(128, 32, 1), tb, 0, stream>>>(w1, W1T, D_MODEL, D_FF, 0, 0);
  transpose_pack_b<<<dim3(32, 128, 1), tb, 0, stream>>>(w2, W2T, D_FF, D_MODEL, 0, 0);

  // LN1
  ln_kernel<<<NROWS, 256, 0, stream>>>(x, ln1g, ln1b, xn);
  // QKV
  gemm128<0><<<dim3(3 * D_MODEL / 128, NROWS / 128), 256, 0, stream>>>(
      xn, WqkvT, NROWS, 3 * D_MODEL, D_MODEL, bq, bk, bv, nullptr, q, k, v);
  // attention
  attn_kernel<<<dim3(SEQ / 64, BATCH * N_HEADS), 256, 0, stream>>>(q, k, v, o);
  // output proj + residual
  gemm128<1><<<dim3(D_MODEL / 128, NROWS / 128), 256, 0, stream>>>(
      o, WpT, NROWS, D_MODEL, D_MODEL, bp, nullptr, nullptr, x, x2, nullptr, nullptr);
  // LN2
  ln_kernel<<<NROWS, 256, 0, stream>>>(x2, ln2g, ln2b, xn2);
  // FF1 (relu)
  gemm128<2><<<dim3(D_FF / 128, NROWS / 128), 256, 0, stream>>>(
      xn2, W1T, NROWS, D_FF, D_MODEL, b1, nullptr, nullptr, nullptr, hbuf, nullptr, nullptr);
  // FF2 + residual -> out
  gemm128<3><<<dim3(D_MODEL / 128, NROWS / 128), 256, 0, stream>>>(
      hbuf, W2T, NROWS, D_MODEL, D_FF, b2, nullptr, nullptr, x2, out, nullptr, nullptr);
}

// Round 2
// 512.959 us; speedup vs baseline: 1.4470x; 1.4470x over previous
//
#include <hip/hip_runtime.h>
#include <hip/hip_bf16.h>

// ---------------- problem constants ----------------
#define D_MODEL 1024
#define N_HEADS 16
#define D_HEAD  64
#define D_FF    4096
#define SEQ     2048
#define BATCH   4
#define NROWS   (BATCH * SEQ)   // 8192

typedef __attribute__((ext_vector_type(8))) short short8;   // 8 x bf16 (4 VGPR)
typedef __attribute__((ext_vector_type(4))) float f32x4;    // mfma accumulator

static __device__ __forceinline__ ushort f2bf(float x) {
  __hip_bfloat16 h = __float2bfloat16(x);
  return *reinterpret_cast<ushort*>(&h);
}

// ---------------- weight packing: out[n][k] (bf16) = in[k][n] (f32) ----------------
__global__ __launch_bounds__(256) void transpose_pack_b(
    const float* __restrict__ in, ushort* __restrict__ out,
    int K, int N, size_t in_bs, size_t out_bs) {
  in  += (size_t)blockIdx.z * in_bs;
  out += (size_t)blockIdx.z * out_bs;
  __shared__ float tile[32][33];
  int n0 = blockIdx.x * 32, k0 = blockIdx.y * 32;
  int tx = threadIdx.x, ty = threadIdx.y;
#pragma unroll
  for (int i = 0; i < 32; i += 8)
    tile[ty + i][tx] = in[(size_t)(k0 + ty + i) * N + n0 + tx];
  __syncthreads();
#pragma unroll
  for (int i = 0; i < 32; i += 8)
    out[(size_t)(n0 + ty + i) * K + k0 + tx] = f2bf(tile[tx][ty + i]);
}

// ---------------- V transpose: v[b,s,h,d] -> vt[b,h,d,s] ----------------
// grid (SEQ/64, BATCH*N_HEADS), block (64,4)
__global__ __launch_bounds__(256) void transpose_v(
    const ushort* __restrict__ v, ushort* __restrict__ vt) {
  const int s0 = blockIdx.x * 64;
  const int bh = blockIdx.y, bb = bh >> 4, hh = bh & 15;
  __shared__ ushort tile[64][66];
  const ushort* src = v + (size_t)bb * SEQ * D_MODEL + (size_t)hh * 64;
  const int tx = threadIdx.x;
#pragma unroll
  for (int i = threadIdx.y; i < 64; i += 4)
    tile[i][tx] = src[(size_t)(s0 + i) * D_MODEL + tx];
  __syncthreads();
  ushort* dst = vt + (size_t)bh * 64 * SEQ + s0;
#pragma unroll
  for (int d = threadIdx.y; d < 64; d += 4)
    dst[(size_t)d * SEQ + tx] = tile[tx][d];
}

// ---------------- LayerNorm (f32 in, bf16 out) ----------------
__global__ __launch_bounds__(256) void ln_kernel(
    const float* __restrict__ x, const float* __restrict__ g,
    const float* __restrict__ b, ushort* __restrict__ out) {
  int row = blockIdx.x, t = threadIdx.x;
  const float4 v = *(const float4*)(x + (size_t)row * D_MODEL + t * 4);
  float s  = v.x + v.y + v.z + v.w;
  float ss = v.x * v.x + v.y * v.y + v.z * v.z + v.w * v.w;
#pragma unroll
  for (int off = 1; off < 64; off <<= 1) {
    s  += __shfl_xor(s, off, 64);
    ss += __shfl_xor(ss, off, 64);
  }
  __shared__ float rs_[4], rss_[4];
  int w = t >> 6;
  if ((t & 63) == 0) { rs_[w] = s; rss_[w] = ss; }
  __syncthreads();
  s  = rs_[0] + rs_[1] + rs_[2] + rs_[3];
  ss = rss_[0] + rss_[1] + rss_[2] + rss_[3];
  float mu  = s * (1.0f / D_MODEL);
  float var = ss * (1.0f / D_MODEL) - mu * mu;
  float rstd = rsqrtf(var + 1e-5f);
  float4 gg = *(const float4*)(g + t * 4);
  float4 bb = *(const float4*)(b + t * 4);
  ushort4 r;
  r.x = f2bf((v.x - mu) * rstd * gg.x + bb.x);
  r.y = f2bf((v.y - mu) * rstd * gg.y + bb.y);
  r.z = f2bf((v.z - mu) * rstd * gg.z + bb.z);
  r.w = f2bf((v.w - mu) * rstd * gg.w + bb.w);
  *(ushort4*)(out + (size_t)row * D_MODEL + t * 4) = r;
}

// ---------------- 128x128 bf16 MFMA GEMM, C = A[M][K] * BT[N][K]^T ----------------
template <int MODE>
__global__ __launch_bounds__(256) void gemm128(
    const ushort* __restrict__ A, const ushort* __restrict__ BT,
    int M, int N, int K,
    const float* __restrict__ bias0, const float* __restrict__ bias1,
    const float* __restrict__ bias2, const float* __restrict__ resid,
    void* __restrict__ out0, void* __restrict__ out1, void* __restrict__ out2) {
  __shared__ __align__(16) ushort As[128 * 32];
  __shared__ __align__(16) ushort Bs[128 * 32];
  const int bm = blockIdx.y, bn = blockIdx.x;
  const int t = threadIdx.x, lane = t & 63, w = t >> 6;
  const int wr = w >> 1, wc = w & 1;
  const int l16 = lane & 15, l4 = lane >> 4;

  f32x4 acc[4][4] = {};

  for (int k0 = 0; k0 < K; k0 += 32) {
    __syncthreads();
#pragma unroll
    for (int i = 0; i < 2; ++i) {
      int c = i * 256 + t;
      int row = c >> 2, e0 = (c & 3) * 8;
      *(uint4*)&As[row * 32 + e0] =
          *(const uint4*)&A[(size_t)(bm * 128 + row) * K + k0 + e0];
      *(uint4*)&Bs[row * 32 + e0] =
          *(const uint4*)&BT[(size_t)(bn * 128 + row) * K + k0 + e0];
    }
    __syncthreads();
    short8 a[4], b[4];
#pragma unroll
    for (int m = 0; m < 4; ++m)
      a[m] = *(const short8*)&As[(wr * 64 + m * 16 + l16) * 32 + l4 * 8];
#pragma unroll
    for (int n = 0; n < 4; ++n)
      b[n] = *(const short8*)&Bs[(wc * 64 + n * 16 + l16) * 32 + l4 * 8];
#pragma unroll
    for (int m = 0; m < 4; ++m)
#pragma unroll
      for (int n = 0; n < 4; ++n)
        acc[m][n] = __builtin_amdgcn_mfma_f32_16x16x32_bf16(a[m], b[n], acc[m][n], 0, 0, 0);
  }

  const int row0 = bm * 128 + wr * 64, col0 = bn * 128 + wc * 64;
#pragma unroll
  for (int m = 0; m < 4; ++m) {
#pragma unroll
    for (int n = 0; n < 4; ++n) {
      int col = col0 + n * 16 + l16;
      if (MODE == 0) {
        int which = col >> 10;
        int c = col & 1023;
        const float* bp_ = (which == 0) ? bias0 : (which == 1) ? bias1 : bias2;
        ushort* op = (which == 0) ? (ushort*)out0 : (which == 1) ? (ushort*)out1 : (ushort*)out2;
        float scale = (which == 0) ? 0.125f : 1.0f;   // fold 1/sqrt(64) into q
#pragma unroll
        for (int i = 0; i < 4; ++i) {
          int row = row0 + m * 16 + l4 * 4 + i;
          float val = (acc[m][n][i] + bp_[c]) * scale;
          op[(size_t)row * D_MODEL + c] = f2bf(val);
        }
      } else if (MODE == 1 || MODE == 3) {
#pragma unroll
        for (int i = 0; i < 4; ++i) {
          int row = row0 + m * 16 + l4 * 4 + i;
          size_t idx = (size_t)row * D_MODEL + col;
          ((float*)out0)[idx] = acc[m][n][i] + bias0[col] + resid[idx];
        }
      } else {  // MODE 2: FF1 relu
#pragma unroll
        for (int i = 0; i < 4; ++i) {
          int row = row0 + m * 16 + l4 * 4 + i;
          float val = fmaxf(acc[m][n][i] + bias0[col], 0.0f);
          ((ushort*)out0)[(size_t)row * D_FF + col] = f2bf(val);
        }
      }
    }
  }
}

// ---------------- causal flash attention v2: swapped operands, no barriers ----------
// grid 1024 blocks x 256 threads (4 independent waves). Each wave owns 32 q rows.
// block b: bh = b&63; p = b>>6; wave w: j = 2p + (w&1); qc = (w<2) ? j : 63-j.
// Q/K/O layout [b,s,h*64+d]; Vt layout [b*16+h][d][s] (pre-transposed).
__global__ __launch_bounds__(256) void attn2_kernel(
    const ushort* __restrict__ Q, const ushort* __restrict__ Km,
    const ushort* __restrict__ Vt, ushort* __restrict__ O) {
  const int t = threadIdx.x, lane = t & 63, w = t >> 6;
  const int l16 = lane & 15, l4 = lane >> 4;
  const int b = blockIdx.x;
  const int bh = b & 63;
  const int p = b >> 6;
  const int j = 2 * p + (w & 1);
  const int qc = (w < 2) ? j : (63 - j);
  const int bb = bh >> 4, hh = bh & 15;
  const size_t base  = (size_t)bb * SEQ * D_MODEL + (size_t)hh * 64;
  const size_t vbase = (size_t)bh * 64 * SEQ;
  const int qb = qc * 32;

  __shared__ __align__(16) ushort Pw[4][32 * 64];
  ushort* myP = &Pw[w][0];

  // Q fragments as mfma B-operand (BT layout: col=q, contiguous d). q pre-scaled 1/8.
  short8 bq[2][2];
#pragma unroll
  for (int qj = 0; qj < 2; ++qj)
#pragma unroll
    for (int dk = 0; dk < 2; ++dk)
      bq[qj][dk] = *(const short8*)&Q[base + (size_t)(qb + qj * 16 + l16) * D_MODEL + dk * 32 + l4 * 8];

  f32x4 oacc[4][2] = {};   // [d-subtile][qj], O^T: col=q(l16), row=d(l4*4+i)
  float m_i[2] = {-1e30f, -1e30f}, l_i[2] = {0.0f, 0.0f};

  const int nt = qc / 2 + 1;
  for (int kt = 0; kt < nt; ++kt) {
    const int kv0 = kt * 64;

    // S^T = mfma(K, Q): rows=kv, cols=q
    f32x4 sacc[2][4] = {};
#pragma unroll
    for (int n = 0; n < 4; ++n)
#pragma unroll
      for (int dk = 0; dk < 2; ++dk) {
        short8 ak = *(const short8*)&Km[base + (size_t)(kv0 + n * 16 + l16) * D_MODEL + dk * 32 + l4 * 8];
        sacc[0][n] = __builtin_amdgcn_mfma_f32_16x16x32_bf16(ak, bq[0][dk], sacc[0][n], 0, 0, 0);
        sacc[1][n] = __builtin_amdgcn_mfma_f32_16x16x32_bf16(ak, bq[1][dk], sacc[1][n], 0, 0, 0);
      }

    const bool diag = (kt == nt - 1);   // only the last tile straddles the diagonal
#pragma unroll
    for (int qj = 0; qj < 2; ++qj) {
      const int q  = qb + qj * 16 + l16;
      const int ql = qj * 16 + l16;
      if (diag) {
#pragma unroll
        for (int n = 0; n < 4; ++n)
#pragma unroll
          for (int i = 0; i < 4; ++i) {
            int kv = kv0 + n * 16 + l4 * 4 + i;
            if (kv > q) sacc[qj][n][i] = -1e30f;
          }
      }
      float mx = -1e30f;
#pragma unroll
      for (int n = 0; n < 4; ++n)
#pragma unroll
        for (int i = 0; i < 4; ++i) mx = fmaxf(mx, sacc[qj][n][i]);
      mx = fmaxf(mx, __shfl_xor(mx, 16, 64));
      mx = fmaxf(mx, __shfl_xor(mx, 32, 64));
      float mnew  = fmaxf(m_i[qj], mx);
      float alpha = __expf(m_i[qj] - mnew);
      m_i[qj] = mnew;
      float lsum = 0.0f;
#pragma unroll
      for (int n = 0; n < 4; ++n) {
        float p0 = __expf(sacc[qj][n][0] - mnew);
        float p1 = __expf(sacc[qj][n][1] - mnew);
        float p2 = __expf(sacc[qj][n][2] - mnew);
        float p3 = __expf(sacc[qj][n][3] - mnew);
        lsum += p0 + p1 + p2 + p3;
        ushort4 pk;
        pk.x = f2bf(p0); pk.y = f2bf(p1); pk.z = f2bf(p2); pk.w = f2bf(p3);
        // P[q][kv], kv XOR-swizzled in 8-granules by row
        *(ushort4*)&myP[ql * 64 + ((n * 16 + l4 * 4) ^ ((ql & 7) * 8))] = pk;
      }
      lsum += __shfl_xor(lsum, 16, 64);
      lsum += __shfl_xor(lsum, 32, 64);
      l_i[qj] = l_i[qj] * alpha + lsum;
#pragma unroll
      for (int nd = 0; nd < 4; ++nd)
#pragma unroll
        for (int i = 0; i < 4; ++i) oacc[nd][qj][i] *= alpha;
    }

    // O^T += mfma(Vt, P): rows=d, cols=q  (same-wave LDS dep; compiler inserts waitcnt)
#pragma unroll
    for (int kk = 0; kk < 2; ++kk) {
      short8 bp[2];
#pragma unroll
      for (int qj = 0; qj < 2; ++qj) {
        int ql = qj * 16 + l16;
        bp[qj] = *(const short8*)&myP[ql * 64 + ((kk * 32 + l4 * 8) ^ ((ql & 7) * 8))];
      }
#pragma unroll
      for (int nd = 0; nd < 4; ++nd) {
        short8 av = *(const short8*)&Vt[vbase + (size_t)(nd * 16 + l16) * SEQ + kv0 + kk * 32 + l4 * 8];
        oacc[nd][0] = __builtin_amdgcn_mfma_f32_16x16x32_bf16(av, bp[0], oacc[nd][0], 0, 0, 0);
        oacc[nd][1] = __builtin_amdgcn_mfma_f32_16x16x32_bf16(av, bp[1], oacc[nd][1], 0, 0, 0);
      }
    }
  }

  // store O: lane owns col q = qb+qj*16+l16, rows d = nd*16 + l4*4 + i (4 contiguous)
#pragma unroll
  for (int qj = 0; qj < 2; ++qj) {
    const int q = qb + qj * 16 + l16;
    float inv = 1.0f / l_i[qj];
#pragma unroll
    for (int nd = 0; nd < 4; ++nd) {
      ushort4 r;
      r.x = f2bf(oacc[nd][qj][0] * inv);
      r.y = f2bf(oacc[nd][qj][1] * inv);
      r.z = f2bf(oacc[nd][qj][2] * inv);
      r.w = f2bf(oacc[nd][qj][3] * inv);
      *(ushort4*)&O[base + (size_t)q * D_MODEL + nd * 16 + l4 * 4] = r;
    }
  }
}

// ---------------- host launch ----------------
extern "C" void kernel_launch(void* const* d_in, const int* in_sizes, int n_in,
                              void* d_out, int out_size, void* d_ws, size_t ws_size,
                              hipStream_t stream) {
  const float* x    = (const float*)d_in[0];
  const float* ln1g = (const float*)d_in[1];
  const float* ln1b = (const float*)d_in[2];
  const float* wq   = (const float*)d_in[3];
  const float* bq   = (const float*)d_in[4];
  const float* wk   = (const float*)d_in[5];
  const float* bk   = (const float*)d_in[6];
  const float* wv   = (const float*)d_in[7];
  const float* bv   = (const float*)d_in[8];
  const float* wp   = (const float*)d_in[9];
  const float* bp   = (const float*)d_in[10];
  const float* ln2g = (const float*)d_in[11];
  const float* ln2b = (const float*)d_in[12];
  const float* w1   = (const float*)d_in[13];
  const float* b1   = (const float*)d_in[14];
  const float* w2   = (const float*)d_in[15];
  const float* b2   = (const float*)d_in[16];
  float* out = (float*)d_out;

  char* base = (char*)d_ws;
  size_t off = 0;
  auto alloc = [&](size_t bytes) -> void* {
    void* r = base + off;
    off += (bytes + 255) & ~(size_t)255;
    return r;
  };
  ushort* WqkvT = (ushort*)alloc((size_t)3 * D_MODEL * D_MODEL * 2);
  ushort* WpT   = (ushort*)alloc((size_t)D_MODEL * D_MODEL * 2);
  ushort* W1T   = (ushort*)alloc((size_t)D_FF * D_MODEL * 2);
  ushort* W2T   = (ushort*)alloc((size_t)D_MODEL * D_FF * 2);
  ushort* xn    = (ushort*)alloc((size_t)NROWS * D_MODEL * 2);
  ushort* q     = (ushort*)alloc((size_t)NROWS * D_MODEL * 2);
  ushort* k     = (ushort*)alloc((size_t)NROWS * D_MODEL * 2);
  ushort* v     = (ushort*)alloc((size_t)NROWS * D_MODEL * 2);
  ushort* o     = (ushort*)alloc((size_t)NROWS * D_MODEL * 2);
  float*  x2    = (float*) alloc((size_t)NROWS * D_MODEL * 4);
  ushort* xn2   = (ushort*)alloc((size_t)NROWS * D_MODEL * 2);
  ushort* hbuf  = (ushort*)alloc((size_t)NROWS * D_FF * 2);
  // vt aliases xn: xn's last read (QKV GEMM) precedes transpose_v in stream order
  ushort* vt = xn;

  dim3 tb(32, 8);
  transpose_pack_b<<<dim3(2, 32, 16), tb, 0, stream>>>(wq, WqkvT + (size_t)0 * D_MODEL * D_MODEL,
      D_MODEL, D_HEAD, (size_t)D_MODEL * D_HEAD, (size_t)D_HEAD * D_MODEL);
  transpose_pack_b<<<dim3(2, 32, 16), tb, 0, stream>>>(wk, WqkvT + (size_t)1 * D_MODEL * D_MODEL,
      D_MODEL, D_HEAD, (size_t)D_MODEL * D_HEAD, (size_t)D_HEAD * D_MODEL);
  transpose_pack_b<<<dim3(2, 32, 16), tb, 0, stream>>>(wv, WqkvT + (size_t)2 * D_MODEL * D_MODEL,
      D_MODEL, D_HEAD, (size_t)D_MODEL * D_HEAD, (size_t)D_HEAD * D_MODEL);
  transpose_pack_b<<<dim3(32, 32, 1), tb, 0, stream>>>(wp, WpT, D_MODEL, D_MODEL, 0, 0);
  transpose_pack_b<<<dim3(128, 32, 1), tb, 0, stream>>>(w1, W1T, D_MODEL, D_FF, 0, 0);
  transpose_pack_b<<<dim3(32, 128, 1), tb, 0, stream>>>(w2, W2T, D_FF, D_MODEL, 0, 0);

  ln_kernel<<<NROWS, 256, 0, stream>>>(x, ln1g, ln1b, xn);
  gemm128<0><<<dim3(3 * D_MODEL / 128, NROWS / 128), 256, 0, stream>>>(
      xn, WqkvT, NROWS, 3 * D_MODEL, D_MODEL, bq, bk, bv, nullptr, q, k, v);
  transpose_v<<<dim3(SEQ / 64, BATCH * N_HEADS), dim3(64, 4), 0, stream>>>(v, vt);
  attn2_kernel<<<1024, 256, 0, stream>>>(q, k, vt, o);
  gemm128<1><<<dim3(D_MODEL / 128, NROWS / 128), 256, 0, stream>>>(
      o, WpT, NROWS, D_MODEL, D_MODEL, bp, nullptr, nullptr, x, x2, nullptr, nullptr);
  ln_kernel<<<NROWS, 256, 0, stream>>>(x2, ln2g, ln2b, xn2);
  gemm128<2><<<dim3(D_FF / 128, NROWS / 128), 256, 0, stream>>>(
      xn2, W1T, NROWS, D_FF, D_MODEL, b1, nullptr, nullptr, nullptr, hbuf, nullptr, nullptr);
  gemm128<3><<<dim3(D_MODEL / 128, NROWS / 128), 256, 0, stream>>>(
      hbuf, W2T, NROWS, D_MODEL, D_FF, b2, nullptr, nullptr, x2, out, nullptr, nullptr);
}

// Round 3
// 504.223 us; speedup vs baseline: 1.4720x; 1.0173x over previous
//
#include <hip/hip_runtime.h>
#include <hip/hip_bf16.h>

// ---------------- problem constants ----------------
#define D_MODEL 1024
#define N_HEADS 16
#define D_HEAD  64
#define D_FF    4096
#define SEQ     2048
#define BATCH   4
#define NROWS   (BATCH * SEQ)   // 8192

typedef __attribute__((ext_vector_type(8))) short short8;   // 8 x bf16 (4 VGPR)
typedef __attribute__((ext_vector_type(4))) float f32x4;    // mfma accumulator

static __device__ __forceinline__ ushort f2bf(float x) {
  __hip_bfloat16 h = __float2bfloat16(x);
  return *reinterpret_cast<ushort*>(&h);
}

// async global->LDS, 16B per lane. LDS dest must be wave-uniform base (+lane*16 by HW).
static __device__ __forceinline__ void gl_lds16(const ushort* g, ushort* l) {
  __builtin_amdgcn_global_load_lds(
      (const __attribute__((address_space(1))) void*)g,
      (__attribute__((address_space(3))) void*)l, 16, 0, 0);
}

// ---------------- weight packing: out[n][k] (bf16) = in[k][n] (f32) ----------------
__global__ __launch_bounds__(256) void transpose_pack_b(
    const float* __restrict__ in, ushort* __restrict__ out,
    int K, int N, size_t in_bs, size_t out_bs) {
  in  += (size_t)blockIdx.z * in_bs;
  out += (size_t)blockIdx.z * out_bs;
  __shared__ float tile[32][33];
  int n0 = blockIdx.x * 32, k0 = blockIdx.y * 32;
  int tx = threadIdx.x, ty = threadIdx.y;
#pragma unroll
  for (int i = 0; i < 32; i += 8)
    tile[ty + i][tx] = in[(size_t)(k0 + ty + i) * N + n0 + tx];
  __syncthreads();
#pragma unroll
  for (int i = 0; i < 32; i += 8)
    out[(size_t)(n0 + ty + i) * K + k0 + tx] = f2bf(tile[tx][ty + i]);
}

// ---------------- V transpose: v[b,s,h,d] -> vt[b,h,d,s] ----------------
__global__ __launch_bounds__(256) void transpose_v(
    const ushort* __restrict__ v, ushort* __restrict__ vt) {
  const int s0 = blockIdx.x * 64;
  const int bh = blockIdx.y, bb = bh >> 4, hh = bh & 15;
  __shared__ ushort tile[64][66];
  const ushort* src = v + (size_t)bb * SEQ * D_MODEL + (size_t)hh * 64;
  const int tx = threadIdx.x;
#pragma unroll
  for (int i = threadIdx.y; i < 64; i += 4)
    tile[i][tx] = src[(size_t)(s0 + i) * D_MODEL + tx];
  __syncthreads();
  ushort* dst = vt + (size_t)bh * 64 * SEQ + s0;
#pragma unroll
  for (int d = threadIdx.y; d < 64; d += 4)
    dst[(size_t)d * SEQ + tx] = tile[tx][d];
}

// ---------------- LayerNorm (f32 in, bf16 out) ----------------
__global__ __launch_bounds__(256) void ln_kernel(
    const float* __restrict__ x, const float* __restrict__ g,
    const float* __restrict__ b, ushort* __restrict__ out) {
  int row = blockIdx.x, t = threadIdx.x;
  const float4 v = *(const float4*)(x + (size_t)row * D_MODEL + t * 4);
  float s  = v.x + v.y + v.z + v.w;
  float ss = v.x * v.x + v.y * v.y + v.z * v.z + v.w * v.w;
#pragma unroll
  for (int off = 1; off < 64; off <<= 1) {
    s  += __shfl_xor(s, off, 64);
    ss += __shfl_xor(ss, off, 64);
  }
  __shared__ float rs_[4], rss_[4];
  int w = t >> 6;
  if ((t & 63) == 0) { rs_[w] = s; rss_[w] = ss; }
  __syncthreads();
  s  = rs_[0] + rs_[1] + rs_[2] + rs_[3];
  ss = rss_[0] + rss_[1] + rss_[2] + rss_[3];
  float mu  = s * (1.0f / D_MODEL);
  float var = ss * (1.0f / D_MODEL) - mu * mu;
  float rstd = rsqrtf(var + 1e-5f);
  float4 gg = *(const float4*)(g + t * 4);
  float4 bb = *(const float4*)(b + t * 4);
  ushort4 r;
  r.x = f2bf((v.x - mu) * rstd * gg.x + bb.x);
  r.y = f2bf((v.y - mu) * rstd * gg.y + bb.y);
  r.z = f2bf((v.z - mu) * rstd * gg.z + bb.z);
  r.w = f2bf((v.w - mu) * rstd * gg.w + bb.w);
  *(ushort4*)(out + (size_t)row * D_MODEL + t * 4) = r;
}

// ---------------- 128x128 bf16 MFMA GEMM (m97 structure), C = A * BT^T ----------------
// 1-D grid with bijective XCD swizzle; global_load_lds width-16 staging.
// MODE 0: QKV  (out0/1/2 = q/k/v bf16, q scaled 1/8)   MODE 1/3: f32 resid add
// MODE 2: FF1 relu -> bf16
template <int MODE>
__global__ __launch_bounds__(256) void gemm128(
    const ushort* __restrict__ A, const ushort* __restrict__ BT,
    int M, int N, int K,
    const float* __restrict__ bias0, const float* __restrict__ bias1,
    const float* __restrict__ bias2, const float* __restrict__ resid,
    void* __restrict__ out0, void* __restrict__ out1, void* __restrict__ out2) {
  __shared__ __align__(16) ushort As[128 * 32];
  __shared__ __align__(16) ushort Bs[128 * 32];
  const int gx = N >> 7;
  const int nwg = gx * (M >> 7);
  const int cpx = nwg >> 3;
  const int tile = (blockIdx.x & 7) * cpx + (blockIdx.x >> 3);
  const int bn = tile % gx, bm = tile / gx;

  const int t = threadIdx.x, lane = t & 63, w = t >> 6;
  const int wr = w >> 1, wc = w & 1;
  const int l16 = lane & 15, l4 = lane >> 4;

  // staging addresses: thread t, round i -> c = i*256+t; row=c>>2, e0=(c&3)*8
  // LDS byte offset = 16*c  ==  wave-uniform base 16*(i*256+w*64) + lane*16
  const int c0 = t, c1 = 256 + t;
  const int ar0 = c0 >> 2, ae0 = (c0 & 3) * 8;
  const int ar1 = c1 >> 2, ae1 = (c1 & 3) * 8;
  const ushort* Ab = A + (size_t)(bm * 128) * K;
  const ushort* Bb = BT + (size_t)(bn * 128) * K;
  ushort* AsW0 = &As[(0 * 256 + w * 64) * 8];
  ushort* AsW1 = &As[(1 * 256 + w * 64) * 8];
  ushort* BsW0 = &Bs[(0 * 256 + w * 64) * 8];
  ushort* BsW1 = &Bs[(1 * 256 + w * 64) * 8];

  f32x4 acc[4][4] = {};

  for (int k0 = 0; k0 < K; k0 += 32) {
    __syncthreads();  // prev ds_reads done before overwrite
    gl_lds16(&Ab[(size_t)ar0 * K + k0 + ae0], AsW0);
    gl_lds16(&Ab[(size_t)ar1 * K + k0 + ae1], AsW1);
    gl_lds16(&Bb[(size_t)ar0 * K + k0 + ae0], BsW0);
    gl_lds16(&Bb[(size_t)ar1 * K + k0 + ae1], BsW1);
    __syncthreads();  // drains vmcnt(0): staged data visible
    short8 a[4], b[4];
#pragma unroll
    for (int m = 0; m < 4; ++m)
      a[m] = *(const short8*)&As[(wr * 64 + m * 16 + l16) * 32 + l4 * 8];
#pragma unroll
    for (int n = 0; n < 4; ++n)
      b[n] = *(const short8*)&Bs[(wc * 64 + n * 16 + l16) * 32 + l4 * 8];
#pragma unroll
    for (int m = 0; m < 4; ++m)
#pragma unroll
      for (int n = 0; n < 4; ++n)
        acc[m][n] = __builtin_amdgcn_mfma_f32_16x16x32_bf16(a[m], b[n], acc[m][n], 0, 0, 0);
  }

  const int row0 = bm * 128 + wr * 64, col0 = bn * 128 + wc * 64;
#pragma unroll
  for (int m = 0; m < 4; ++m) {
#pragma unroll
    for (int n = 0; n < 4; ++n) {
      int col = col0 + n * 16 + l16;
      if (MODE == 0) {
        int which = col >> 10;
        int c = col & 1023;
        const float* bp_ = (which == 0) ? bias0 : (which == 1) ? bias1 : bias2;
        ushort* op = (which == 0) ? (ushort*)out0 : (which == 1) ? (ushort*)out1 : (ushort*)out2;
        float scale = (which == 0) ? 0.125f : 1.0f;   // fold 1/sqrt(64) into q
#pragma unroll
        for (int i = 0; i < 4; ++i) {
          int row = row0 + m * 16 + l4 * 4 + i;
          float val = (acc[m][n][i] + bp_[c]) * scale;
          op[(size_t)row * D_MODEL + c] = f2bf(val);
        }
      } else if (MODE == 1 || MODE == 3) {
#pragma unroll
        for (int i = 0; i < 4; ++i) {
          int row = row0 + m * 16 + l4 * 4 + i;
          size_t idx = (size_t)row * D_MODEL + col;
          ((float*)out0)[idx] = acc[m][n][i] + bias0[col] + resid[idx];
        }
      } else {  // MODE 2: FF1 relu
#pragma unroll
        for (int i = 0; i < 4; ++i) {
          int row = row0 + m * 16 + l4 * 4 + i;
          float val = fmaxf(acc[m][n][i] + bias0[col], 0.0f);
          ((ushort*)out0)[(size_t)row * D_FF + col] = f2bf(val);
        }
      }
    }
  }
}

// ---------------- causal flash attention v2: swapped operands, no barriers ----------
__global__ __launch_bounds__(256) void attn2_kernel(
    const ushort* __restrict__ Q, const ushort* __restrict__ Km,
    const ushort* __restrict__ Vt, ushort* __restrict__ O) {
  const int t = threadIdx.x, lane = t & 63, w = t >> 6;
  const int l16 = lane & 15, l4 = lane >> 4;
  const int b = blockIdx.x;
  const int bh = b & 63;
  const int p = b >> 6;
  const int j = 2 * p + (w & 1);
  const int qc = (w < 2) ? j : (63 - j);
  const int bb = bh >> 4, hh = bh & 15;
  const size_t base  = (size_t)bb * SEQ * D_MODEL + (size_t)hh * 64;
  const size_t vbase = (size_t)bh * 64 * SEQ;
  const int qb = qc * 32;

  __shared__ __align__(16) ushort Pw[4][32 * 64];
  ushort* myP = &Pw[w][0];

  short8 bq[2][2];
#pragma unroll
  for (int qj = 0; qj < 2; ++qj)
#pragma unroll
    for (int dk = 0; dk < 2; ++dk)
      bq[qj][dk] = *(const short8*)&Q[base + (size_t)(qb + qj * 16 + l16) * D_MODEL + dk * 32 + l4 * 8];

  f32x4 oacc[4][2] = {};
  float m_i[2] = {-1e30f, -1e30f}, l_i[2] = {0.0f, 0.0f};

  const int nt = qc / 2 + 1;
  for (int kt = 0; kt < nt; ++kt) {
    const int kv0 = kt * 64;

    // S^T = mfma(K, Q): rows=kv, cols=q
    f32x4 sacc[2][4] = {};
    __builtin_amdgcn_s_setprio(1);
#pragma unroll
    for (int n = 0; n < 4; ++n)
#pragma unroll
      for (int dk = 0; dk < 2; ++dk) {
        short8 ak = *(const short8*)&Km[base + (size_t)(kv0 + n * 16 + l16) * D_MODEL + dk * 32 + l4 * 8];
        sacc[0][n] = __builtin_amdgcn_mfma_f32_16x16x32_bf16(ak, bq[0][dk], sacc[0][n], 0, 0, 0);
        sacc[1][n] = __builtin_amdgcn_mfma_f32_16x16x32_bf16(ak, bq[1][dk], sacc[1][n], 0, 0, 0);
      }
    __builtin_amdgcn_s_setprio(0);

    const bool diag = (kt == nt - 1);
#pragma unroll
    for (int qj = 0; qj < 2; ++qj) {
      const int q  = qb + qj * 16 + l16;
      const int ql = qj * 16 + l16;
      if (diag) {
#pragma unroll
        for (int n = 0; n < 4; ++n)
#pragma unroll
          for (int i = 0; i < 4; ++i) {
            int kv = kv0 + n * 16 + l4 * 4 + i;
            if (kv > q) sacc[qj][n][i] = -1e30f;
          }
      }
      float mx = -1e30f;
#pragma unroll
      for (int n = 0; n < 4; ++n)
#pragma unroll
        for (int i = 0; i < 4; ++i) mx = fmaxf(mx, sacc[qj][n][i]);
      mx = fmaxf(mx, __shfl_xor(mx, 16, 64));
      mx = fmaxf(mx, __shfl_xor(mx, 32, 64));
      float mnew  = fmaxf(m_i[qj], mx);
      float alpha = __expf(m_i[qj] - mnew);
      m_i[qj] = mnew;
      float lsum = 0.0f;
#pragma unroll
      for (int n = 0; n < 4; ++n) {
        float p0 = __expf(sacc[qj][n][0] - mnew);
        float p1 = __expf(sacc[qj][n][1] - mnew);
        float p2 = __expf(sacc[qj][n][2] - mnew);
        float p3 = __expf(sacc[qj][n][3] - mnew);
        lsum += p0 + p1 + p2 + p3;
        ushort4 pk;
        pk.x = f2bf(p0); pk.y = f2bf(p1); pk.z = f2bf(p2); pk.w = f2bf(p3);
        *(ushort4*)&myP[ql * 64 + ((n * 16 + l4 * 4) ^ ((ql & 7) * 8))] = pk;
      }
      lsum += __shfl_xor(lsum, 16, 64);
      lsum += __shfl_xor(lsum, 32, 64);
      l_i[qj] = l_i[qj] * alpha + lsum;
#pragma unroll
      for (int nd = 0; nd < 4; ++nd)
#pragma unroll
        for (int i = 0; i < 4; ++i) oacc[nd][qj][i] *= alpha;
    }

    // O^T += mfma(Vt, P)
    __builtin_amdgcn_s_setprio(1);
#pragma unroll
    for (int kk = 0; kk < 2; ++kk) {
      short8 bp[2];
#pragma unroll
      for (int qj = 0; qj < 2; ++qj) {
        int ql = qj * 16 + l16;
        bp[qj] = *(const short8*)&myP[ql * 64 + ((kk * 32 + l4 * 8) ^ ((ql & 7) * 8))];
      }
#pragma unroll
      for (int nd = 0; nd < 4; ++nd) {
        short8 av = *(const short8*)&Vt[vbase + (size_t)(nd * 16 + l16) * SEQ + kv0 + kk * 32 + l4 * 8];
        oacc[nd][0] = __builtin_amdgcn_mfma_f32_16x16x32_bf16(av, bp[0], oacc[nd][0], 0, 0, 0);
        oacc[nd][1] = __builtin_amdgcn_mfma_f32_16x16x32_bf16(av, bp[1], oacc[nd][1], 0, 0, 0);
      }
    }
    __builtin_amdgcn_s_setprio(0);
  }

#pragma unroll
  for (int qj = 0; qj < 2; ++qj) {
    const int q = qb + qj * 16 + l16;
    float inv = 1.0f / l_i[qj];
#pragma unroll
    for (int nd = 0; nd < 4; ++nd) {
      ushort4 r;
      r.x = f2bf(oacc[nd][qj][0] * inv);
      r.y = f2bf(oacc[nd][qj][1] * inv);
      r.z = f2bf(oacc[nd][qj][2] * inv);
      r.w = f2bf(oacc[nd][qj][3] * inv);
      *(ushort4*)&O[base + (size_t)q * D_MODEL + nd * 16 + l4 * 4] = r;
    }
  }
}

// ---------------- host launch ----------------
extern "C" void kernel_launch(void* const* d_in, const int* in_sizes, int n_in,
                              void* d_out, int out_size, void* d_ws, size_t ws_size,
                              hipStream_t stream) {
  const float* x    = (const float*)d_in[0];
  const float* ln1g = (const float*)d_in[1];
  const float* ln1b = (const float*)d_in[2];
  const float* wq   = (const float*)d_in[3];
  const float* bq   = (const float*)d_in[4];
  const float* wk   = (const float*)d_in[5];
  const float* bk   = (const float*)d_in[6];
  const float* wv   = (const float*)d_in[7];
  const float* bv   = (const float*)d_in[8];
  const float* wp   = (const float*)d_in[9];
  const float* bp   = (const float*)d_in[10];
  const float* ln2g = (const float*)d_in[11];
  const float* ln2b = (const float*)d_in[12];
  const float* w1   = (const float*)d_in[13];
  const float* b1   = (const float*)d_in[14];
  const float* w2   = (const float*)d_in[15];
  const float* b2   = (const float*)d_in[16];
  float* out = (float*)d_out;

  char* base = (char*)d_ws;
  size_t off = 0;
  auto alloc = [&](size_t bytes) -> void* {
    void* r = base + off;
    off += (bytes + 255) & ~(size_t)255;
    return r;
  };
  ushort* WqkvT = (ushort*)alloc((size_t)3 * D_MODEL * D_MODEL * 2);
  ushort* WpT   = (ushort*)alloc((size_t)D_MODEL * D_MODEL * 2);
  ushort* W1T   = (ushort*)alloc((size_t)D_FF * D_MODEL * 2);
  ushort* W2T   = (ushort*)alloc((size_t)D_MODEL * D_FF * 2);
  ushort* xn    = (ushort*)alloc((size_t)NROWS * D_MODEL * 2);
  ushort* q     = (ushort*)alloc((size_t)NROWS * D_MODEL * 2);
  ushort* k     = (ushort*)alloc((size_t)NROWS * D_MODEL * 2);
  ushort* v     = (ushort*)alloc((size_t)NROWS * D_MODEL * 2);
  ushort* o     = (ushort*)alloc((size_t)NROWS * D_MODEL * 2);
  float*  x2    = (float*) alloc((size_t)NROWS * D_MODEL * 4);
  ushort* xn2   = (ushort*)alloc((size_t)NROWS * D_MODEL * 2);
  ushort* hbuf  = (ushort*)alloc((size_t)NROWS * D_FF * 2);
  ushort* vt = xn;  // alias: xn's last read (QKV GEMM) precedes transpose_v

  dim3 tb(32, 8);
  transpose_pack_b<<<dim3(2, 32, 16), tb, 0, stream>>>(wq, WqkvT + (size_t)0 * D_MODEL * D_MODEL,
      D_MODEL, D_HEAD, (size_t)D_MODEL * D_HEAD, (size_t)D_HEAD * D_MODEL);
  transpose_pack_b<<<dim3(2, 32, 16), tb, 0, stream>>>(wk, WqkvT + (size_t)1 * D_MODEL * D_MODEL,
      D_MODEL, D_HEAD, (size_t)D_MODEL * D_HEAD, (size_t)D_HEAD * D_MODEL);
  transpose_pack_b<<<dim3(2, 32, 16), tb, 0, stream>>>(wv, WqkvT + (size_t)2 * D_MODEL * D_MODEL,
      D_MODEL, D_HEAD, (size_t)D_MODEL * D_HEAD, (size_t)D_HEAD * D_MODEL);
  transpose_pack_b<<<dim3(32, 32, 1), tb, 0, stream>>>(wp, WpT, D_MODEL, D_MODEL, 0, 0);
  transpose_pack_b<<<dim3(128, 32, 1), tb, 0, stream>>>(w1, W1T, D_MODEL, D_FF, 0, 0);
  transpose_pack_b<<<dim3(32, 128, 1), tb, 0, stream>>>(w2, W2T, D_FF, D_MODEL, 0, 0);

  ln_kernel<<<NROWS, 256, 0, stream>>>(x, ln1g, ln1b, xn);
  gemm128<0><<<dim3(3 * D_MODEL / 128 * (NROWS / 128)), 256, 0, stream>>>(
      xn, WqkvT, NROWS, 3 * D_MODEL, D_MODEL, bq, bk, bv, nullptr, q, k, v);
  transpose_v<<<dim3(SEQ / 64, BATCH * N_HEADS), dim3(64, 4), 0, stream>>>(v, vt);
  attn2_kernel<<<1024, 256, 0, stream>>>(q, k, vt, o);
  gemm128<1><<<dim3(D_MODEL / 128 * (NROWS / 128)), 256, 0, stream>>>(
      o, WpT, NROWS, D_MODEL, D_MODEL, bp, nullptr, nullptr, x, x2, nullptr, nullptr);
  ln_kernel<<<NROWS, 256, 0, stream>>>(x2, ln2g, ln2b, xn2);
  gemm128<2><<<dim3(D_FF / 128 * (NROWS / 128)), 256, 0, stream>>>(
      xn2, W1T, NROWS, D_FF, D_MODEL, b1, nullptr, nullptr, nullptr, hbuf, nullptr, nullptr);
  gemm128<3><<<dim3(D_MODEL / 128 * (NROWS / 128)), 256, 0, stream>>>(
      hbuf, W2T, NROWS, D_MODEL, D_FF, b2, nullptr, nullptr, x2, out, nullptr, nullptr);
}

// Round 4
// 465.257 us; speedup vs baseline: 1.5953x; 1.0838x over previous
//
#include <hip/hip_runtime.h>
#include <hip/hip_bf16.h>

// ---------------- problem constants ----------------
#define D_MODEL 1024
#define N_HEADS 16
#define D_HEAD  64
#define D_FF    4096
#define SEQ     2048
#define BATCH   4
#define NROWS   (BATCH * SEQ)   // 8192

typedef __attribute__((ext_vector_type(8))) short short8;   // 8 x bf16 (4 VGPR)
typedef __attribute__((ext_vector_type(4))) float f32x4;    // mfma accumulator

#if defined(__has_builtin) && __has_builtin(__builtin_amdgcn_exp2f)
#define EXP2(x) __builtin_amdgcn_exp2f(x)
#else
#define EXP2(x) exp2f(x)
#endif

static __device__ __forceinline__ ushort f2bf(float x) {
  __hip_bfloat16 h = __float2bfloat16(x);
  return *reinterpret_cast<ushort*>(&h);
}

// async global->LDS, 16B per lane. LDS dest is wave-uniform base (+lane*16 by HW).
static __device__ __forceinline__ void gl_lds16(const ushort* g, ushort* l) {
  __builtin_amdgcn_global_load_lds(
      (const __attribute__((address_space(1))) void*)g,
      (__attribute__((address_space(3))) void*)l, 16, 0, 0);
}

// ---------------- weight packing: out[n][k] (bf16) = in[k][n] (f32) ----------------
__global__ __launch_bounds__(256) void transpose_pack_b(
    const float* __restrict__ in, ushort* __restrict__ out,
    int K, int N, size_t in_bs, size_t out_bs) {
  in  += (size_t)blockIdx.z * in_bs;
  out += (size_t)blockIdx.z * out_bs;
  __shared__ float tile[32][33];
  int n0 = blockIdx.x * 32, k0 = blockIdx.y * 32;
  int tx = threadIdx.x, ty = threadIdx.y;
#pragma unroll
  for (int i = 0; i < 32; i += 8)
    tile[ty + i][tx] = in[(size_t)(k0 + ty + i) * N + n0 + tx];
  __syncthreads();
#pragma unroll
  for (int i = 0; i < 32; i += 8)
    out[(size_t)(n0 + ty + i) * K + k0 + tx] = f2bf(tile[tx][ty + i]);
}

// ---------------- V transpose: v[b,s,h,d] -> vt[b,h,d,s] ----------------
__global__ __launch_bounds__(256) void transpose_v(
    const ushort* __restrict__ v, ushort* __restrict__ vt) {
  const int s0 = blockIdx.x * 64;
  const int bh = blockIdx.y, bb = bh >> 4, hh = bh & 15;
  __shared__ ushort tile[64][66];
  const ushort* src = v + (size_t)bb * SEQ * D_MODEL + (size_t)hh * 64;
  const int tx = threadIdx.x;
#pragma unroll
  for (int i = threadIdx.y; i < 64; i += 4)
    tile[i][tx] = src[(size_t)(s0 + i) * D_MODEL + tx];
  __syncthreads();
  ushort* dst = vt + (size_t)bh * 64 * SEQ + s0;
#pragma unroll
  for (int d = threadIdx.y; d < 64; d += 4)
    dst[(size_t)d * SEQ + tx] = tile[tx][d];
}

// ---------------- LayerNorm (f32 in, bf16 out) ----------------
__global__ __launch_bounds__(256) void ln_kernel(
    const float* __restrict__ x, const float* __restrict__ g,
    const float* __restrict__ b, ushort* __restrict__ out) {
  int row = blockIdx.x, t = threadIdx.x;
  const float4 v = *(const float4*)(x + (size_t)row * D_MODEL + t * 4);
  float s  = v.x + v.y + v.z + v.w;
  float ss = v.x * v.x + v.y * v.y + v.z * v.z + v.w * v.w;
#pragma unroll
  for (int off = 1; off < 64; off <<= 1) {
    s  += __shfl_xor(s, off, 64);
    ss += __shfl_xor(ss, off, 64);
  }
  __shared__ float rs_[4], rss_[4];
  int w = t >> 6;
  if ((t & 63) == 0) { rs_[w] = s; rss_[w] = ss; }
  __syncthreads();
  s  = rs_[0] + rs_[1] + rs_[2] + rs_[3];
  ss = rss_[0] + rss_[1] + rss_[2] + rss_[3];
  float mu  = s * (1.0f / D_MODEL);
  float var = ss * (1.0f / D_MODEL) - mu * mu;
  float rstd = rsqrtf(var + 1e-5f);
  float4 gg = *(const float4*)(g + t * 4);
  float4 bb = *(const float4*)(b + t * 4);
  ushort4 r;
  r.x = f2bf((v.x - mu) * rstd * gg.x + bb.x);
  r.y = f2bf((v.y - mu) * rstd * gg.y + bb.y);
  r.z = f2bf((v.z - mu) * rstd * gg.z + bb.z);
  r.w = f2bf((v.w - mu) * rstd * gg.w + bb.w);
  *(ushort4*)(out + (size_t)row * D_MODEL + t * 4) = r;
}

// ---------------- 256x256 bf16 MFMA GEMM, deep-pipelined double-buffer ----------------
// BM=BN=256, BK=64, 8 waves (2M x 4N), LDS 128 KiB (2 x (A+B) tiles).
// Per K-tile: issue all 8 prefetch gl_lds early -> 64 MFMA/wave -> vmcnt(0) -> 1 barrier.
// T2 XOR-swizzle (16B granule ^ (row&7)) via pre-swizzled global source + swizzled ds_read.
// MODE 0: QKV (out0/1/2 = q/k/v bf16; q scaled 0.125*log2e)   MODE 2: FF1 relu -> bf16
template <int MODE>
__global__ __launch_bounds__(512, 2) void gemm256(
    const ushort* __restrict__ A, const ushort* __restrict__ BT,
    int M, int N, int K,
    const float* __restrict__ bias0, const float* __restrict__ bias1,
    const float* __restrict__ bias2,
    void* __restrict__ out0, void* __restrict__ out1, void* __restrict__ out2) {
  __shared__ __align__(16) ushort As[2][256 * 64];
  __shared__ __align__(16) ushort Bs[2][256 * 64];
  const int gx = N >> 8;
  const int nwg = gx * (M >> 8);
  const int cpx = nwg >> 3;
  const int tile = (blockIdx.x & 7) * cpx + (blockIdx.x >> 3);
  const int bn = tile % gx, bm = tile / gx;
  const int t = threadIdx.x, lane = t & 63, w = t >> 6;
  const int wr = w >> 2, wc = w & 3;
  const int l16 = lane & 15, l4 = lane >> 4;

  const ushort* Ab = A + (size_t)(bm * 256) * K;
  const ushort* Bb = BT + (size_t)(bn * 256) * K;

  // staging map round i: granule c = i*512+t; LDS linear granule c; row=c>>3;
  // source granule within row = (c&7) ^ (row&7)  (pre-swizzled source, linear dest)
  int srow[4], scol[4];
#pragma unroll
  for (int i = 0; i < 4; ++i) {
    int c = i * 512 + t;
    srow[i] = c >> 3;
    scol[i] = 8 * ((c & 7) ^ ((c >> 3) & 7));
  }

  f32x4 acc[8][4] = {};
  int cur = 0;
  const int nk = K >> 6;

  // prologue: stage K-tile 0 into buffer 0
#pragma unroll
  for (int i = 0; i < 4; ++i) {
    ushort* ldst = (ushort*)&As[0][(i * 512 + w * 64) * 8];
    gl_lds16(&Ab[(size_t)srow[i] * K + scol[i]], ldst);
    ushort* ldstB = (ushort*)&Bs[0][(i * 512 + w * 64) * 8];
    gl_lds16(&Bb[(size_t)srow[i] * K + scol[i]], ldstB);
  }
  asm volatile("s_waitcnt vmcnt(0)" ::: "memory");
  __syncthreads();

  for (int kt = 0; kt < nk; ++kt) {
    // issue next K-tile's loads FIRST (async, into the other buffer)
    if (kt + 1 < nk) {
      const int k0n = (kt + 1) << 6;
#pragma unroll
      for (int i = 0; i < 4; ++i) {
        gl_lds16(&Ab[(size_t)srow[i] * K + k0n + scol[i]], (ushort*)&As[cur ^ 1][(i * 512 + w * 64) * 8]);
        gl_lds16(&Bb[(size_t)srow[i] * K + k0n + scol[i]], (ushort*)&Bs[cur ^ 1][(i * 512 + w * 64) * 8]);
      }
    }
    const ushort* As_ = As[cur];
    const ushort* Bs_ = Bs[cur];
    short8 bfr[4][2];
#pragma unroll
    for (int n = 0; n < 4; ++n) {
      const int row = wc * 64 + n * 16 + l16;
      const int sw = (row & 7) * 8;
      bfr[n][0] = *(const short8*)&Bs_[row * 64 + ((l4 * 8) ^ sw)];
      bfr[n][1] = *(const short8*)&Bs_[row * 64 + ((l4 * 8 + 32) ^ sw)];
    }
#pragma unroll
    for (int m = 0; m < 8; ++m) {
      const int row = wr * 128 + m * 16 + l16;
      const int sw = (row & 7) * 8;
      short8 a0 = *(const short8*)&As_[row * 64 + ((l4 * 8) ^ sw)];
      short8 a1 = *(const short8*)&As_[row * 64 + ((l4 * 8 + 32) ^ sw)];
#pragma unroll
      for (int n = 0; n < 4; ++n) {
        acc[m][n] = __builtin_amdgcn_mfma_f32_16x16x32_bf16(a0, bfr[n][0], acc[m][n], 0, 0, 0);
        acc[m][n] = __builtin_amdgcn_mfma_f32_16x16x32_bf16(a1, bfr[n][1], acc[m][n], 0, 0, 0);
      }
    }
    // drain next-tile loads (covered by the 64 MFMAs above), then single barrier
    asm volatile("s_waitcnt vmcnt(0)" ::: "memory");
    __syncthreads();
    cur ^= 1;
  }

  // epilogue
  const int row0 = bm * 256 + wr * 128, col0 = bn * 256 + wc * 64;
#pragma unroll
  for (int m = 0; m < 8; ++m) {
#pragma unroll
    for (int n = 0; n < 4; ++n) {
      const int col = col0 + n * 16 + l16;
      if (MODE == 0) {
        const int which = col >> 10;
        const int c = col & 1023;
        const float* bp_ = (which == 0) ? bias0 : (which == 1) ? bias1 : bias2;
        ushort* op = (which == 0) ? (ushort*)out0 : (which == 1) ? (ushort*)out1 : (ushort*)out2;
        // q: fold 1/sqrt(64) * log2(e) so attention can use exp2
        const float scale = (which == 0) ? 0.125f * 1.44269504f : 1.0f;
#pragma unroll
        for (int i = 0; i < 4; ++i) {
          const int row = row0 + m * 16 + l4 * 4 + i;
          op[(size_t)row * D_MODEL + c] = f2bf((acc[m][n][i] + bp_[c]) * scale);
        }
      } else {  // MODE 2: FF1 relu -> bf16
#pragma unroll
        for (int i = 0; i < 4; ++i) {
          const int row = row0 + m * 16 + l4 * 4 + i;
          const float val = fmaxf(acc[m][n][i] + bias0[col], 0.0f);
          ((ushort*)out0)[(size_t)row * D_FF + col] = f2bf(val);
        }
      }
    }
  }
}

// ---------------- 128x128 bf16 MFMA GEMM (m97 structure) for FF2 / proj -------------
// MODE 1: PROJ (out0 f32 = resid + C + bias0)   MODE 3: FF2 (same)
template <int MODE>
__global__ __launch_bounds__(256) void gemm128(
    const ushort* __restrict__ A, const ushort* __restrict__ BT,
    int M, int N, int K,
    const float* __restrict__ bias0, const float* __restrict__ resid,
    float* __restrict__ out0) {
  __shared__ __align__(16) ushort As[128 * 32];
  __shared__ __align__(16) ushort Bs[128 * 32];
  const int gx = N >> 7;
  const int nwg = gx * (M >> 7);
  const int cpx = nwg >> 3;
  const int tile = (blockIdx.x & 7) * cpx + (blockIdx.x >> 3);
  const int bn = tile % gx, bm = tile / gx;

  const int t = threadIdx.x, lane = t & 63, w = t >> 6;
  const int wr = w >> 1, wc = w & 1;
  const int l16 = lane & 15, l4 = lane >> 4;

  const int c0 = t, c1 = 256 + t;
  const int ar0 = c0 >> 2, ae0 = (c0 & 3) * 8;
  const int ar1 = c1 >> 2, ae1 = (c1 & 3) * 8;
  const ushort* Ab = A + (size_t)(bm * 128) * K;
  const ushort* Bb = BT + (size_t)(bn * 128) * K;
  ushort* AsW0 = &As[(0 * 256 + w * 64) * 8];
  ushort* AsW1 = &As[(1 * 256 + w * 64) * 8];
  ushort* BsW0 = &Bs[(0 * 256 + w * 64) * 8];
  ushort* BsW1 = &Bs[(1 * 256 + w * 64) * 8];

  f32x4 acc[4][4] = {};

  for (int k0 = 0; k0 < K; k0 += 32) {
    __syncthreads();
    gl_lds16(&Ab[(size_t)ar0 * K + k0 + ae0], AsW0);
    gl_lds16(&Ab[(size_t)ar1 * K + k0 + ae1], AsW1);
    gl_lds16(&Bb[(size_t)ar0 * K + k0 + ae0], BsW0);
    gl_lds16(&Bb[(size_t)ar1 * K + k0 + ae1], BsW1);
    __syncthreads();
    short8 a[4], b[4];
#pragma unroll
    for (int m = 0; m < 4; ++m)
      a[m] = *(const short8*)&As[(wr * 64 + m * 16 + l16) * 32 + l4 * 8];
#pragma unroll
    for (int n = 0; n < 4; ++n)
      b[n] = *(const short8*)&Bs[(wc * 64 + n * 16 + l16) * 32 + l4 * 8];
#pragma unroll
    for (int m = 0; m < 4; ++m)
#pragma unroll
      for (int n = 0; n < 4; ++n)
        acc[m][n] = __builtin_amdgcn_mfma_f32_16x16x32_bf16(a[m], b[n], acc[m][n], 0, 0, 0);
  }

  const int row0 = bm * 128 + wr * 64, col0 = bn * 128 + wc * 64;
#pragma unroll
  for (int m = 0; m < 4; ++m) {
#pragma unroll
    for (int n = 0; n < 4; ++n) {
      const int col = col0 + n * 16 + l16;
#pragma unroll
      for (int i = 0; i < 4; ++i) {
        const int row = row0 + m * 16 + l4 * 4 + i;
        const size_t idx = (size_t)row * D_MODEL + col;
        out0[idx] = acc[m][n][i] + bias0[col] + resid[idx];
      }
    }
  }
}

// ---------------- causal flash attention: swapped operands, no barriers --------------
// grid 1024 blocks x 256 threads (4 independent waves), each wave owns 32 q rows.
// scores already in log2 domain (q pre-scaled by 0.125*log2e) -> exp2 softmax.
__global__ __launch_bounds__(256) void attn2_kernel(
    const ushort* __restrict__ Q, const ushort* __restrict__ Km,
    const ushort* __restrict__ Vt, ushort* __restrict__ O) {
  const int t = threadIdx.x, lane = t & 63, w = t >> 6;
  const int l16 = lane & 15, l4 = lane >> 4;
  const int b = blockIdx.x;
  const int bh = b & 63;
  const int p = b >> 6;
  const int j = 2 * p + (w & 1);
  const int qc = (w < 2) ? j : (63 - j);
  const int bb = bh >> 4, hh = bh & 15;
  const size_t base  = (size_t)bb * SEQ * D_MODEL + (size_t)hh * 64;
  const size_t vbase = (size_t)bh * 64 * SEQ;
  const int qb = qc * 32;

  __shared__ __align__(16) ushort Pw[4][32 * 64];
  ushort* myP = &Pw[w][0];

  short8 bq[2][2];
#pragma unroll
  for (int qj = 0; qj < 2; ++qj)
#pragma unroll
    for (int dk = 0; dk < 2; ++dk)
      bq[qj][dk] = *(const short8*)&Q[base + (size_t)(qb + qj * 16 + l16) * D_MODEL + dk * 32 + l4 * 8];

  f32x4 oacc[4][2] = {};
  float m_i[2] = {-1e30f, -1e30f}, l_i[2] = {0.0f, 0.0f};

  const int nt = qc / 2 + 1;
  for (int kt = 0; kt < nt; ++kt) {
    const int kv0 = kt * 64;

    // S^T = mfma(K, Q): rows=kv, cols=q
    f32x4 sacc[2][4] = {};
#pragma unroll
    for (int n = 0; n < 4; ++n)
#pragma unroll
      for (int dk = 0; dk < 2; ++dk) {
        short8 ak = *(const short8*)&Km[base + (size_t)(kv0 + n * 16 + l16) * D_MODEL + dk * 32 + l4 * 8];
        sacc[0][n] = __builtin_amdgcn_mfma_f32_16x16x32_bf16(ak, bq[0][dk], sacc[0][n], 0, 0, 0);
        sacc[1][n] = __builtin_amdgcn_mfma_f32_16x16x32_bf16(ak, bq[1][dk], sacc[1][n], 0, 0, 0);
      }

    const bool diag = (kt == nt - 1);
#pragma unroll
    for (int qj = 0; qj < 2; ++qj) {
      const int q  = qb + qj * 16 + l16;
      const int ql = qj * 16 + l16;
      if (diag) {
#pragma unroll
        for (int n = 0; n < 4; ++n)
#pragma unroll
          for (int i = 0; i < 4; ++i) {
            int kv = kv0 + n * 16 + l4 * 4 + i;
            if (kv > q) sacc[qj][n][i] = -1e30f;
          }
      }
      float mx = -1e30f;
#pragma unroll
      for (int n = 0; n < 4; ++n)
#pragma unroll
        for (int i = 0; i < 4; ++i) mx = fmaxf(mx, sacc[qj][n][i]);
      mx = fmaxf(mx, __shfl_xor(mx, 16, 64));
      mx = fmaxf(mx, __shfl_xor(mx, 32, 64));
      float mnew  = fmaxf(m_i[qj], mx);
      float alpha = EXP2(m_i[qj] - mnew);
      m_i[qj] = mnew;
      float lsum = 0.0f;
#pragma unroll
      for (int n = 0; n < 4; ++n) {
        float p0 = EXP2(sacc[qj][n][0] - mnew);
        float p1 = EXP2(sacc[qj][n][1] - mnew);
        float p2 = EXP2(sacc[qj][n][2] - mnew);
        float p3 = EXP2(sacc[qj][n][3] - mnew);
        lsum += p0 + p1 + p2 + p3;
        ushort4 pk;
        pk.x = f2bf(p0); pk.y = f2bf(p1); pk.z = f2bf(p2); pk.w = f2bf(p3);
        *(ushort4*)&myP[ql * 64 + ((n * 16 + l4 * 4) ^ ((ql & 7) * 8))] = pk;
      }
      lsum += __shfl_xor(lsum, 16, 64);
      lsum += __shfl_xor(lsum, 32, 64);
      l_i[qj] = l_i[qj] * alpha + lsum;
#pragma unroll
      for (int nd = 0; nd < 4; ++nd)
#pragma unroll
        for (int i = 0; i < 4; ++i) oacc[nd][qj][i] *= alpha;
    }

    // O^T += mfma(Vt, P)
#pragma unroll
    for (int kk = 0; kk < 2; ++kk) {
      short8 bp[2];
#pragma unroll
      for (int qj = 0; qj < 2; ++qj) {
        int ql = qj * 16 + l16;
        bp[qj] = *(const short8*)&myP[ql * 64 + ((kk * 32 + l4 * 8) ^ ((ql & 7) * 8))];
      }
#pragma unroll
      for (int nd = 0; nd < 4; ++nd) {
        short8 av = *(const short8*)&Vt[vbase + (size_t)(nd * 16 + l16) * SEQ + kv0 + kk * 32 + l4 * 8];
        oacc[nd][0] = __builtin_amdgcn_mfma_f32_16x16x32_bf16(av, bp[0], oacc[nd][0], 0, 0, 0);
        oacc[nd][1] = __builtin_amdgcn_mfma_f32_16x16x32_bf16(av, bp[1], oacc[nd][1], 0, 0, 0);
      }
    }
  }

#pragma unroll
  for (int qj = 0; qj < 2; ++qj) {
    const int q = qb + qj * 16 + l16;
    float inv = 1.0f / l_i[qj];
#pragma unroll
    for (int nd = 0; nd < 4; ++nd) {
      ushort4 r;
      r.x = f2bf(oacc[nd][qj][0] * inv);
      r.y = f2bf(oacc[nd][qj][1] * inv);
      r.z = f2bf(oacc[nd][qj][2] * inv);
      r.w = f2bf(oacc[nd][qj][3] * inv);
      *(ushort4*)&O[base + (size_t)q * D_MODEL + nd * 16 + l4 * 4] = r;
    }
  }
}

// ---------------- host launch ----------------
extern "C" void kernel_launch(void* const* d_in, const int* in_sizes, int n_in,
                              void* d_out, int out_size, void* d_ws, size_t ws_size,
                              hipStream_t stream) {
  const float* x    = (const float*)d_in[0];
  const float* ln1g = (const float*)d_in[1];
  const float* ln1b = (const float*)d_in[2];
  const float* wq   = (const float*)d_in[3];
  const float* bq   = (const float*)d_in[4];
  const float* wk   = (const float*)d_in[5];
  const float* bk   = (const float*)d_in[6];
  const float* wv   = (const float*)d_in[7];
  const float* bv   = (const float*)d_in[8];
  const float* wp   = (const float*)d_in[9];
  const float* bp   = (const float*)d_in[10];
  const float* ln2g = (const float*)d_in[11];
  const float* ln2b = (const float*)d_in[12];
  const float* w1   = (const float*)d_in[13];
  const float* b1   = (const float*)d_in[14];
  const float* w2   = (const float*)d_in[15];
  const float* b2   = (const float*)d_in[16];
  float* out = (float*)d_out;

  char* base = (char*)d_ws;
  size_t off = 0;
  auto alloc = [&](size_t bytes) -> void* {
    void* r = base + off;
    off += (bytes + 255) & ~(size_t)255;
    return r;
  };
  ushort* WqkvT = (ushort*)alloc((size_t)3 * D_MODEL * D_MODEL * 2);
  ushort* WpT   = (ushort*)alloc((size_t)D_MODEL * D_MODEL * 2);
  ushort* W1T   = (ushort*)alloc((size_t)D_FF * D_MODEL * 2);
  ushort* W2T   = (ushort*)alloc((size_t)D_MODEL * D_FF * 2);
  ushort* xn    = (ushort*)alloc((size_t)NROWS * D_MODEL * 2);
  ushort* q     = (ushort*)alloc((size_t)NROWS * D_MODEL * 2);
  ushort* k     = (ushort*)alloc((size_t)NROWS * D_MODEL * 2);
  ushort* v     = (ushort*)alloc((size_t)NROWS * D_MODEL * 2);
  ushort* o     = (ushort*)alloc((size_t)NROWS * D_MODEL * 2);
  float*  x2    = (float*) alloc((size_t)NROWS * D_MODEL * 4);
  ushort* xn2   = (ushort*)alloc((size_t)NROWS * D_MODEL * 2);
  ushort* hbuf  = (ushort*)alloc((size_t)NROWS * D_FF * 2);
  ushort* vt = xn;  // alias: xn's last read (QKV GEMM) precedes transpose_v

  dim3 tb(32, 8);
  transpose_pack_b<<<dim3(2, 32, 16), tb, 0, stream>>>(wq, WqkvT + (size_t)0 * D_MODEL * D_MODEL,
      D_MODEL, D_HEAD, (size_t)D_MODEL * D_HEAD, (size_t)D_HEAD * D_MODEL);
  transpose_pack_b<<<dim3(2, 32, 16), tb, 0, stream>>>(wk, WqkvT + (size_t)1 * D_MODEL * D_MODEL,
      D_MODEL, D_HEAD, (size_t)D_MODEL * D_HEAD, (size_t)D_HEAD * D_MODEL);
  transpose_pack_b<<<dim3(2, 32, 16), tb, 0, stream>>>(wv, WqkvT + (size_t)2 * D_MODEL * D_MODEL,
      D_MODEL, D_HEAD, (size_t)D_MODEL * D_HEAD, (size_t)D_HEAD * D_MODEL);
  transpose_pack_b<<<dim3(32, 32, 1), tb, 0, stream>>>(wp, WpT, D_MODEL, D_MODEL, 0, 0);
  transpose_pack_b<<<dim3(128, 32, 1), tb, 0, stream>>>(w1, W1T, D_MODEL, D_FF, 0, 0);
  transpose_pack_b<<<dim3(32, 128, 1), tb, 0, stream>>>(w2, W2T, D_FF, D_MODEL, 0, 0);

  ln_kernel<<<NROWS, 256, 0, stream>>>(x, ln1g, ln1b, xn);
  // QKV: 256^2 tiles, 32x12 = 384 blocks
  gemm256<0><<<dim3((NROWS / 256) * (3 * D_MODEL / 256)), 512, 0, stream>>>(
      xn, WqkvT, NROWS, 3 * D_MODEL, D_MODEL, bq, bk, bv, q, k, v);
  transpose_v<<<dim3(SEQ / 64, BATCH * N_HEADS), dim3(64, 4), 0, stream>>>(v, vt);
  attn2_kernel<<<1024, 256, 0, stream>>>(q, k, vt, o);
  // proj: 128^2 tiles
  gemm128<1><<<dim3((NROWS / 128) * (D_MODEL / 128)), 256, 0, stream>>>(
      o, WpT, NROWS, D_MODEL, D_MODEL, bp, x, x2);
  ln_kernel<<<NROWS, 256, 0, stream>>>(x2, ln2g, ln2b, xn2);
  // FF1: 256^2 tiles, 32x16 = 512 blocks
  gemm256<2><<<dim3((NROWS / 256) * (D_FF / 256)), 512, 0, stream>>>(
      xn2, W1T, NROWS, D_FF, D_MODEL, b1, nullptr, nullptr, hbuf, nullptr, nullptr);
  // FF2: 128^2 tiles
  gemm128<3><<<dim3((NROWS / 128) * (D_MODEL / 128)), 256, 0, stream>>>(
      hbuf, W2T, NROWS, D_MODEL, D_FF, b2, x2, out);
}